// Round 4
// baseline (114.527 us; speedup 1.0000x reference)
//
#include <hip/hip_runtime.h>

// KDA delta-rule state update, B=H=32, K=V=256, fp32.
// out[k,v] = g[k]*S[k,v] + beta*key[k]*(val[v] - kt[v]),
// kt[v] = sum_k key[k]*g[k]*S[k,v]   (column-independent in v).
//
// V split into 8 slices of 32 -> 256-thread blocks own a 256x32 sub-tile
// in registers (8 f32x4/thread, ~32 data VGPRs). launch_bounds(256,8)
// targets <=64 VGPR -> 8 resident blocks/CU (32 waves) so many blocks'
// load/store phases interleave and keep the HBM pipe continuously busy.

#define KD 256
#define VD 256
#define SW 8    // f32x4 columns per slice (32 floats)

typedef float f32x4 __attribute__((ext_vector_type(4)));

__global__ __launch_bounds__(256, 8)
void kda_update_kernel(const float* __restrict__ state,
                       const float* __restrict__ keys,
                       const float* __restrict__ values,
                       const float* __restrict__ gates,
                       const float* __restrict__ beta,
                       float* __restrict__ out)
{
    const int bh    = blockIdx.x >> 3;   // (b,h) tile
    const int slice = blockIdx.x & 7;    // v-slice within tile
    const size_t tile_off = (size_t)bh * (KD * VD);
    const f32x4* __restrict__ S4 = (const f32x4*)(state + tile_off);
    f32x4* __restrict__ O4 = (f32x4*)(out + tile_off);

    __shared__ float s_g[KD];           // alpha
    __shared__ float s_w[KD];           // alpha * key
    __shared__ float s_c[KD];           // beta * key
    __shared__ f32x4 s_part[32][SW];    // per-rowgroup kt partials (4 KiB)
    __shared__ f32x4 s_red[8][SW];      // stage-1 reduce (1 KiB)
    __shared__ f32x4 s_kt[SW];          // final kt for this slice

    const int t  = threadIdx.x;
    const int c  = t & (SW - 1);        // f32x4 col within slice
    const int r0 = t >> 3;              // row group 0..31
    const int c0 = slice * SW;          // slice's f32x4 col offset

    // Per-row scalars (256 threads, 256 rows: one each).
    {
        const float g = gates[bh * KD + t];
        const float k = keys[bh * KD + t];
        s_g[t] = g;
        s_w[t] = g * k;
        s_c[t] = beta[bh] * k;
    }

    // Load sub-tile: thread (r0,c) owns rows k = r0 + 32j, f32x4-col c0+c.
    // Each 8-lane group reads one aligned 128 B line -> fully coalesced.
    f32x4 s[8];
#pragma unroll
    for (int j = 0; j < 8; ++j) {
        s[j] = __builtin_nontemporal_load(&S4[(size_t)(r0 + 32 * j) * (VD / 4) + c0 + c]);
    }

    __syncthreads();  // scalars ready

    // Phase 1: per-thread partial kt over this thread's 8 rows.
    f32x4 p = (f32x4)(0.f);
#pragma unroll
    for (int j = 0; j < 8; ++j) {
        const float w = s_w[r0 + 32 * j];
        p.x = fmaf(w, s[j].x, p.x);
        p.y = fmaf(w, s[j].y, p.y);
        p.z = fmaf(w, s[j].z, p.z);
        p.w = fmaf(w, s[j].w, p.w);
    }
    s_part[r0][c] = p;
    __syncthreads();

    // Two-stage cross-rowgroup reduce: 64 threads sum 4 each, then 8 sum 8.
    if (t < 64) {
        const int col = t & (SW - 1);
        const int q   = t >> 3;          // 0..7
        f32x4 acc = s_part[q * 4 + 0][col];
#pragma unroll
        for (int i = 1; i < 4; ++i) {
            const f32x4 u = s_part[q * 4 + i][col];
            acc.x += u.x; acc.y += u.y; acc.z += u.z; acc.w += u.w;
        }
        s_red[q][col] = acc;
    }
    __syncthreads();
    if (t < SW) {
        f32x4 acc = s_red[0][t];
#pragma unroll
        for (int i = 1; i < 8; ++i) {
            const f32x4 u = s_red[i][t];
            acc.x += u.x; acc.y += u.y; acc.z += u.z; acc.w += u.w;
        }
        s_kt[t] = acc;
    }
    __syncthreads();

    // Phase 2: output from registers (no HBM re-read).
    const f32x4 kt = s_kt[c];
    const f32x4 vv = ((const f32x4*)(values + (size_t)bh * VD))[c0 + c];
    f32x4 d;
    d.x = vv.x - kt.x; d.y = vv.y - kt.y; d.z = vv.z - kt.z; d.w = vv.w - kt.w;

#pragma unroll
    for (int j = 0; j < 8; ++j) {
        const int k = r0 + 32 * j;
        const float g  = s_g[k];
        const float cb = s_c[k];
        f32x4 o;
        o.x = fmaf(g, s[j].x, cb * d.x);
        o.y = fmaf(g, s[j].y, cb * d.y);
        o.z = fmaf(g, s[j].z, cb * d.z);
        o.w = fmaf(g, s[j].w, cb * d.w);
        __builtin_nontemporal_store(o, &O4[(size_t)k * (VD / 4) + c0 + c]);
    }
}

extern "C" void kernel_launch(void* const* d_in, const int* in_sizes, int n_in,
                              void* d_out, int out_size, void* d_ws, size_t ws_size,
                              hipStream_t stream) {
    const float* state  = (const float*)d_in[0];
    const float* keys   = (const float*)d_in[1];
    const float* values = (const float*)d_in[2];
    const float* gates  = (const float*)d_in[3];
    const float* beta   = (const float*)d_in[4];
    float* out = (float*)d_out;

    dim3 grid(32 * 32 * 8);  // (b,h) x 8 v-slices
    dim3 block(256);
    hipLaunchKernelGGL(kda_update_kernel, grid, block, 0, stream,
                       state, keys, values, gates, beta, out);
}

// Round 5
// 105.208 us; speedup vs baseline: 1.0886x; 1.0886x over previous
//
#include <hip/hip_runtime.h>

// KDA delta-rule state update, B=H=32, K=V=256, fp32.
// out[k,v] = g[k]*S[k,v] + beta*key[k]*(val[v] - kt[v]),
// kt[v] = sum_k g[k]*key[k]*S[k,v]   (column-independent in v).
//
// Each 256-thread block handles TWO 32-float v-slices (A,B) of one (b,h)
// tile, software-pipelined: A+B loads issued together; B's loads stay in
// flight across A's reduce/store (lgkm-only barriers, no vmcnt drain), so
// the HBM pipe never gaps on the kt reduction.

#define KD 256
#define VD 256
#define SW 8    // f32x4 columns per slice (32 floats)

typedef float f32x4 __attribute__((ext_vector_type(4)));

__device__ __forceinline__ f32x4 shfl_xor4(f32x4 v, int mask) {
    f32x4 r;
    r.x = __shfl_xor(v.x, mask, 64);
    r.y = __shfl_xor(v.y, mask, 64);
    r.z = __shfl_xor(v.z, mask, 64);
    r.w = __shfl_xor(v.w, mask, 64);
    return r;
}

// barrier that drains LDS ops only -- in-flight global loads/stores survive
__device__ __forceinline__ void lds_barrier() {
    asm volatile("s_waitcnt lgkmcnt(0)" ::: "memory");
    __builtin_amdgcn_s_barrier();
}

__global__ __launch_bounds__(256, 4)
void kda_update_kernel(const float* __restrict__ state,
                       const float* __restrict__ keys,
                       const float* __restrict__ values,
                       const float* __restrict__ gates,
                       const float* __restrict__ beta,
                       float* __restrict__ out)
{
    const int bid = blockIdx.x;
    const int bh  = bid >> 2;        // (b,h) tile
    const int sp  = bid & 3;         // slice pair -> slices 2sp, 2sp+1
    const size_t toff = (size_t)bh * (KD * VD);
    const f32x4* __restrict__ S4 = (const f32x4*)(state + toff);
    f32x4* __restrict__ O4 = (f32x4*)(out + toff);
    const f32x4* __restrict__ V4 = (const f32x4*)(values + (size_t)bh * VD);

    __shared__ float s_g[KD];          // alpha
    __shared__ float s_w[KD];          // alpha*key
    __shared__ float s_c[KD];          // beta*key
    __shared__ f32x4 s_redA[4][SW];    // cross-wave kt partials, slice A
    __shared__ f32x4 s_redB[4][SW];    // cross-wave kt partials, slice B

    const int t    = threadIdx.x;
    const int lane = t & 63;
    const int wv   = t >> 6;           // wave 0..3
    const int c    = t & (SW - 1);     // f32x4 col within slice
    const int r0   = t >> 3;           // rowgroup 0..31
    const int cA   = (2 * sp)     * SW + c;
    const int cB   = (2 * sp + 1) * SW + c;

    // ---- stage per-row scalars FIRST (their vmcnt wait happens before any
    //      tile loads are issued, so it can't drain the pipeline) ----
    {
        const float g = gates[bh * KD + t];
        const float k = keys[bh * KD + t];
        s_g[t] = g;
        s_w[t] = g * k;
        s_c[t] = beta[bh] * k;
    }
    lds_barrier();

    // ---- issue values, then A, then B tile loads (queue order matters:
    //      waiting on A completion leaves B's 8 loads outstanding) ----
    const f32x4 vA = V4[cA];
    const f32x4 vB = V4[cB];

    f32x4 sA[8], sB[8];
#pragma unroll
    for (int j = 0; j < 8; ++j)
        sA[j] = __builtin_nontemporal_load(&S4[(size_t)(r0 + 32 * j) * (VD / 4) + cA]);
#pragma unroll
    for (int j = 0; j < 8; ++j)
        sB[j] = __builtin_nontemporal_load(&S4[(size_t)(r0 + 32 * j) * (VD / 4) + cB]);

    // ---- slice A: partial kt (waits vmcnt(8): B still in flight) ----
    f32x4 p = (f32x4)(0.f);
#pragma unroll
    for (int j = 0; j < 8; ++j) {
        const float w = s_w[r0 + 32 * j];
        p.x = fmaf(w, sA[j].x, p.x);
        p.y = fmaf(w, sA[j].y, p.y);
        p.z = fmaf(w, sA[j].z, p.z);
        p.w = fmaf(w, sA[j].w, p.w);
    }
    // in-wave butterfly over the 8 rowgroups this wave holds
    p += shfl_xor4(p, 8);
    p += shfl_xor4(p, 16);
    p += shfl_xor4(p, 32);
    if (lane < SW) s_redA[wv][lane] = p;   // lane==c for lane<8
    lds_barrier();

    f32x4 ktA = s_redA[0][c];
    {
        const f32x4 q1 = s_redA[1][c], q2 = s_redA[2][c], q3 = s_redA[3][c];
        ktA.x += q1.x + q2.x + q3.x;
        ktA.y += q1.y + q2.y + q3.y;
        ktA.z += q1.z + q2.z + q3.z;
        ktA.w += q1.w + q2.w + q3.w;
    }
    f32x4 dA;
    dA.x = vA.x - ktA.x; dA.y = vA.y - ktA.y; dA.z = vA.z - ktA.z; dA.w = vA.w - ktA.w;

    // ---- store A (NT stores fly while B's reduce happens next) ----
#pragma unroll
    for (int j = 0; j < 8; ++j) {
        const int k = r0 + 32 * j;
        const float g  = s_g[k];
        const float cb = s_c[k];
        f32x4 o;
        o.x = fmaf(g, sA[j].x, cb * dA.x);
        o.y = fmaf(g, sA[j].y, cb * dA.y);
        o.z = fmaf(g, sA[j].z, cb * dA.z);
        o.w = fmaf(g, sA[j].w, cb * dA.w);
        __builtin_nontemporal_store(o, &O4[(size_t)k * (VD / 4) + cA]);
    }

    // ---- slice B: its loads have had A's whole reduce+store to land ----
    f32x4 q = (f32x4)(0.f);
#pragma unroll
    for (int j = 0; j < 8; ++j) {
        const float w = s_w[r0 + 32 * j];
        q.x = fmaf(w, sB[j].x, q.x);
        q.y = fmaf(w, sB[j].y, q.y);
        q.z = fmaf(w, sB[j].z, q.z);
        q.w = fmaf(w, sB[j].w, q.w);
    }
    q += shfl_xor4(q, 8);
    q += shfl_xor4(q, 16);
    q += shfl_xor4(q, 32);
    if (lane < SW) s_redB[wv][lane] = q;
    lds_barrier();

    f32x4 ktB = s_redB[0][c];
    {
        const f32x4 q1 = s_redB[1][c], q2 = s_redB[2][c], q3 = s_redB[3][c];
        ktB.x += q1.x + q2.x + q3.x;
        ktB.y += q1.y + q2.y + q3.y;
        ktB.z += q1.z + q2.z + q3.z;
        ktB.w += q1.w + q2.w + q3.w;
    }
    f32x4 dB;
    dB.x = vB.x - ktB.x; dB.y = vB.y - ktB.y; dB.z = vB.z - ktB.z; dB.w = vB.w - ktB.w;

#pragma unroll
    for (int j = 0; j < 8; ++j) {
        const int k = r0 + 32 * j;
        const float g  = s_g[k];
        const float cb = s_c[k];
        f32x4 o;
        o.x = fmaf(g, sB[j].x, cb * dB.x);
        o.y = fmaf(g, sB[j].y, cb * dB.y);
        o.z = fmaf(g, sB[j].z, cb * dB.z);
        o.w = fmaf(g, sB[j].w, cb * dB.w);
        __builtin_nontemporal_store(o, &O4[(size_t)k * (VD / 4) + cB]);
    }
}

extern "C" void kernel_launch(void* const* d_in, const int* in_sizes, int n_in,
                              void* d_out, int out_size, void* d_ws, size_t ws_size,
                              hipStream_t stream) {
    const float* state  = (const float*)d_in[0];
    const float* keys   = (const float*)d_in[1];
    const float* values = (const float*)d_in[2];
    const float* gates  = (const float*)d_in[3];
    const float* beta   = (const float*)d_in[4];
    float* out = (float*)d_out;

    dim3 grid(32 * 32 * 4);  // (b,h) x 4 slice-pairs
    dim3 block(256);
    hipLaunchKernelGGL(kda_update_kernel, grid, block, 0, stream,
                       state, keys, values, gates, beta, out);
}